// Round 6
// baseline (10162.863 us; speedup 1.0000x reference)
//
#include <hip/hip_runtime.h>

#define B_    128
#define TPAST 1024
#define FN    512
#define TT    1536
#define INF   64
#define IPF   128
#define HD    256
#define NG    1024
#define OUTF  64

typedef _Float16 f16;
typedef _Float16 f16x8 __attribute__((ext_vector_type(8)));
typedef _Float16 f16x4 __attribute__((ext_vector_type(4)));
typedef float    f32x4 __attribute__((ext_vector_type(4)));

__device__ __forceinline__ float sigm_(float x) {
  return __builtin_amdgcn_rcpf(1.f + __expf(-x));
}
__device__ __forceinline__ float tanh_(float x) {
  return 1.f - 2.f * __builtin_amdgcn_rcpf(1.f + __expf(2.f * x));
}
// Opaque 16B load: asm result cannot be rematerialized by the register
// allocator; with a sufficient VGPR budget the value stays resident, and
// under budget failure it degrades to spill/reload (not per-step remat).
__device__ __forceinline__ f16x8 oload16(const f16* p) {
  f16x8 v;
  asm volatile("global_load_dwordx4 %0, %1, off\n\ts_waitcnt vmcnt(0)"
               : "=v"(v) : "v"(p));
  return v;
}

// ---------------------------------------------------------------------------
// prep: fold encoder into past-input weights; fold future encoder into the
// future recurrent matrix; convert weights to f16.
// ---------------------------------------------------------------------------
extern "C" __global__ void eprep(
    const float* __restrict__ enc_W, const float* __restrict__ enc_b,
    const float* __restrict__ fut_W, const float* __restrict__ fut_b,
    const float* __restrict__ dec_W,
    const float* __restrict__ pW_ih, const float* __restrict__ pW_hh,
    const float* __restrict__ pb_ih, const float* __restrict__ pb_hh,
    const float* __restrict__ fW_ih, const float* __restrict__ fW_hh,
    const float* __restrict__ fb_ih, const float* __restrict__ fb_hh,
    f16* __restrict__ Wp_in, float* __restrict__ bp,
    f16* __restrict__ Wp16, f16* __restrict__ Wf16,
    float* __restrict__ bf, f16* __restrict__ dW16)
{
  int stride = gridDim.x * blockDim.x;
  int gid = blockIdx.x * blockDim.x + threadIdx.x;
  // Wf = fW_hh + fW_ih @ fut_W   [1024,256];  Wp16 = (f16)pW_hh
  for (int i = gid; i < NG * HD; i += stride) {
    int n = i >> 8, j = i & 255;
    float s = fW_hh[i];
    for (int m = 0; m < IPF; ++m) s += fW_ih[n * IPF + m] * fut_W[m * HD + j];
    Wf16[i] = (f16)s;
    Wp16[i] = (f16)pW_hh[i];
  }
  // Wp_in = pW_ih @ enc_W   [1024,64]
  for (int i = gid; i < NG * INF; i += stride) {
    int n = i >> 6, k = i & 63;
    float s = 0.f;
    for (int m = 0; m < IPF; ++m) s += pW_ih[n * IPF + m] * enc_W[m * INF + k];
    Wp_in[i] = (f16)s;
  }
  for (int i = gid; i < OUTF * HD; i += stride) dW16[i] = (f16)dec_W[i];
  // bp = pW_ih@enc_b + pb_ih + pb_hh ; bf = fW_ih@fut_b + fb_ih + fb_hh
  for (int n = gid; n < NG; n += stride) {
    float s1 = pb_ih[n] + pb_hh[n], s2 = fb_ih[n] + fb_hh[n];
    for (int m = 0; m < IPF; ++m) {
      s1 += pW_ih[n * IPF + m] * enc_b[m];
      s2 += fW_ih[n * IPF + m] * fut_b[m];
    }
    bp[n] = s1; bf[n] = s2;
  }
}

// ---------------------------------------------------------------------------
// P GEMM: P = x @ Wp_in^T + bp, stored PER-WG CONTIGUOUS:
//   P[((bt*Tc + tl)*NG + n)*16 + blocal]
// ---------------------------------------------------------------------------
extern "C" __global__ __launch_bounds__(64) void epgemm(
    const float* __restrict__ x, const f16* __restrict__ Wp_in,
    const float* __restrict__ bp, f16* __restrict__ P, int t0, int Tc)
{
  int wg = blockIdx.x;
  int tl = wg >> 3, bt = wg & 7;
  int t = t0 + tl;
  int l = (int)threadIdx.x, r = l & 15, g = l >> 4;
  const float* xb = x + ((size_t)(bt * 16 + r) * TPAST + t) * INF;
  f16x8 a[2];
#pragma unroll
  for (int kk = 0; kk < 2; ++kk) {
    const float* px = xb + kk * 32 + g * 8;
    f32x4 v0 = *(const f32x4*)px;
    f32x4 v1 = *(const f32x4*)(px + 4);
#pragma unroll
    for (int e = 0; e < 4; ++e) { a[kk][e] = (f16)v0[e]; a[kk][4 + e] = (f16)v1[e]; }
  }
  f16* Pt = P + ((size_t)bt * Tc + tl) * (NG * 16);
  for (int nt = 0; nt < 64; ++nt) {
    int n = nt * 16 + r;
    f16x8 b0 = *(const f16x8*)(Wp_in + (size_t)n * INF + g * 8);
    f16x8 b1 = *(const f16x8*)(Wp_in + (size_t)n * INF + 32 + g * 8);
    f32x4 acc = {0.f, 0.f, 0.f, 0.f};
    acc = __builtin_amdgcn_mfma_f32_16x16x32_f16(a[0], b0, acc, 0, 0, 0);
    acc = __builtin_amdgcn_mfma_f32_16x16x32_f16(a[1], b1, acc, 0, 0, 0);
    float bias = bp[n];
    f16x4 hv;
#pragma unroll
    for (int e = 0; e < 4; ++e) hv[e] = (f16)(acc[e] + bias);
    *(f16x4*)(Pt + n * 16 + 4 * g) = hv;
  }
}

// ---------------------------------------------------------------------------
// Persistent recurrent kernel. 8 WGs x 512 threads (8 waves, 2 waves/SIMD).
// __launch_bounds__(512, 2): min 2 waves/EU -> 256-VGPR budget via the
// documented HIP path (the separate amdgpu_waves_per_eu attribute was
// ignored; VGPR_Count stayed 128 and the weight fragments were spilled).
// Weight fragments kt0..5 loaded once via opaque asm loads, kt6..7 in
// swizzled LDS (128 KB). h (f16, swizzled) + c (f32, stride-20) in LDS.
// P loads deferred to the kt6 boundary (pv live only across 2 k-tiles,
// keeping peak pressure ~250 <= 256).
// ---------------------------------------------------------------------------
extern "C" __global__ __launch_bounds__(512, 2)
void erecur(
    const f16* __restrict__ W, const f16* __restrict__ P, int pstep,
    const float* __restrict__ bias,
    f16* __restrict__ hs, f16* __restrict__ h_state, float* __restrict__ c_state,
    int Tc, int init_state)
{
  __shared__ f16  Wl[NG * 64];      // 128 KB : W[:, 192:256], swizzled
  __shared__ f16  hb[16 * HD];      //   8 KB : h[b][j], swizzled by b
  __shared__ float cb[HD * 20];     //  20 KB : c[j][b], padded stride 20

  int tid = (int)threadIdx.x;
  int w = tid >> 6, l = tid & 63, r = l & 15, g = l >> 4;
  int b0 = blockIdx.x * 16;

  // LDS-resident W slice (k = 192..255 for all n)
  for (int nn = tid; nn < NG; nn += 512) {
#pragma unroll
    for (int c8 = 0; c8 < 8; ++c8) {
      f16x8 v = *(const f16x8*)(W + (size_t)nn * HD + 192 + c8 * 8);
      *(f16x8*)&Wl[(nn * 64 + c8 * 8) ^ ((nn & 7) << 3)] = v;
    }
  }
  // Register-pinned B-fragments: wave w owns cols [ga*256 + w*32, +32)
  f16x8 wf[4][2][6];
#pragma unroll
  for (int ga = 0; ga < 4; ++ga)
#pragma unroll
    for (int s = 0; s < 2; ++s) {
      int n = ga * 256 + w * 32 + s * 16 + r;
#pragma unroll
      for (int kt = 0; kt < 6; ++kt)
        wf[ga][s][kt] = oload16(W + (size_t)n * HD + kt * 32 + g * 8);
    }
  // Future phase: per-gate bias held in 8 registers, folded into acc init
  float bi[4][2];
  if (!P) {
#pragma unroll
    for (int ga = 0; ga < 4; ++ga)
#pragma unroll
      for (int s = 0; s < 2; ++s)
        bi[ga][s] = bias[ga * 256 + w * 32 + s * 16 + r];
  }
  if (init_state) {
    for (int i = tid; i < 16 * HD; i += 512) hb[i ^ (((i >> 8) & 7) << 3)] = (f16)0.f;
    for (int i = tid; i < HD * 20; i += 512) cb[i] = 0.f;
  } else {
    for (int i = tid; i < 16 * HD; i += 512) {
      int b = i >> 8, j = i & 255;
      hb[i ^ ((b & 7) << 3)] = h_state[(size_t)(b0 + b) * HD + j];
      cb[j * 20 + b] = c_state[(size_t)(b0 + b) * HD + j];
    }
  }
  __syncthreads();

  const f16* Pw = P ? (P + (size_t)blockIdx.x * Tc * pstep) : nullptr;

  for (int tl = 0; tl < Tc; ++tl) {
    f32x4 acc[4][2];
#pragma unroll
    for (int ga = 0; ga < 4; ++ga)
#pragma unroll
      for (int s = 0; s < 2; ++s) {
        float b0i = P ? 0.f : bi[ga][s];
        acc[ga][s][0] = b0i; acc[ga][s][1] = b0i;
        acc[ga][s][2] = b0i; acc[ga][s][3] = b0i;
      }

    // k-tiles 0..5: weights from registers
#pragma unroll
    for (int kt = 0; kt < 6; ++kt) {
      f16x8 a = *(const f16x8*)&hb[(r * HD + kt * 32 + g * 8) ^ ((r & 7) << 3)];
#pragma unroll
      for (int ga = 0; ga < 4; ++ga)
#pragma unroll
        for (int s = 0; s < 2; ++s)
          acc[ga][s] = __builtin_amdgcn_mfma_f32_16x16x32_f16(a, wf[ga][s][kt], acc[ga][s], 0, 0, 0);
    }
    // issue P loads here: pv live only across the 2 LDS k-tiles (~620 cy
    // of MFMA cover), keeping peak register pressure under the 256 cap
    f16x4 pv[4][2];
    if (P) {
#pragma unroll
      for (int ga = 0; ga < 4; ++ga)
#pragma unroll
        for (int s = 0; s < 2; ++s) {
          int n = ga * 256 + w * 32 + s * 16 + r;
          pv[ga][s] = *(const f16x4*)(Pw + n * 16 + 4 * g);
        }
    }
    // k-tiles 6..7: weights from swizzled LDS
#pragma unroll
    for (int kt = 6; kt < 8; ++kt) {
      f16x8 a = *(const f16x8*)&hb[(r * HD + kt * 32 + g * 8) ^ ((r & 7) << 3)];
#pragma unroll
      for (int ga = 0; ga < 4; ++ga)
#pragma unroll
        for (int s = 0; s < 2; ++s) {
          int n = ga * 256 + w * 32 + s * 16 + r;
          f16x8 bw = *(const f16x8*)&Wl[(n * 64 + (kt - 6) * 32 + g * 8) ^ ((n & 7) << 3)];
          acc[ga][s] = __builtin_amdgcn_mfma_f32_16x16x32_f16(a, bw, acc[ga][s], 0, 0, 0);
        }
    }
    __syncthreads();  // all h reads done before h is overwritten

#pragma unroll
    for (int s = 0; s < 2; ++s) {
      int j = w * 32 + s * 16 + r;
      f32x4 cold = *(f32x4*)&cb[j * 20 + 4 * g];
      f32x4 cnew;
      f16 hh[4];
#pragma unroll
      for (int e = 0; e < 4; ++e) {
        float xi = acc[0][s][e], xf = acc[1][s][e], xg = acc[2][s][e], xo = acc[3][s][e];
        if (P) {
          xi += (float)pv[0][s][e]; xf += (float)pv[1][s][e];
          xg += (float)pv[2][s][e]; xo += (float)pv[3][s][e];
        }
        float ii = sigm_(xi), ff = sigm_(xf), oo = sigm_(xo), gg = tanh_(xg);
        float cn = ff * cold[e] + ii * gg;
        cnew[e] = cn;
        hh[e] = (f16)(oo * tanh_(cn));
      }
      *(f32x4*)&cb[j * 20 + 4 * g] = cnew;
#pragma unroll
      for (int e = 0; e < 4; ++e) {
        int b = 4 * g + e;
        hb[(b * HD + j) ^ ((b & 7) << 3)] = hh[e];
        hs[((size_t)tl * B_ + b0 + b) * HD + j] = hh[e];
      }
    }
    __syncthreads();
    if (P) Pw += pstep;
  }
  // persist state for the next phase/chunk
  for (int i = tid; i < 16 * HD; i += 512) {
    int b = i >> 8, j = i & 255;
    h_state[(size_t)(b0 + b) * HD + j] = hb[i ^ ((b & 7) << 3)];
    c_state[(size_t)(b0 + b) * HD + j] = cb[j * 20 + b];
  }
}

// ---------------------------------------------------------------------------
// Decoder GEMM: out[b][t][o] = hs[t][b][:] @ dec_W^T + dec_b.
// ---------------------------------------------------------------------------
extern "C" __global__ __launch_bounds__(64) void edec(
    const f16* __restrict__ hs, const f16* __restrict__ dW,
    const float* __restrict__ dec_b, float* __restrict__ out, int t0, int Tc)
{
  int wg = blockIdx.x;
  int tt = wg >> 7, b = wg & 127;
  int l = (int)threadIdx.x, r = l & 15, g = l >> 4;
  f16x8 wfr[4][8];
#pragma unroll
  for (int nt = 0; nt < 4; ++nt)
#pragma unroll
    for (int kt = 0; kt < 8; ++kt)
      wfr[nt][kt] = *(const f16x8*)(dW + (size_t)(nt * 16 + r) * HD + kt * 32 + g * 8);
  float bb[4];
#pragma unroll
  for (int nt = 0; nt < 4; ++nt) bb[nt] = dec_b[nt * 16 + r];
  f32x4 acc[2][4];
  const f32x4 zero4 = {0.f, 0.f, 0.f, 0.f};
#pragma unroll
  for (int mt = 0; mt < 2; ++mt)
#pragma unroll
    for (int nt = 0; nt < 4; ++nt) acc[mt][nt] = zero4;
#pragma unroll
  for (int mt = 0; mt < 2; ++mt)
#pragma unroll
    for (int kt = 0; kt < 8; ++kt) {
      f16x8 a = *(const f16x8*)(hs + ((size_t)(tt * 32 + mt * 16 + r) * B_ + b) * HD + kt * 32 + g * 8);
#pragma unroll
      for (int nt = 0; nt < 4; ++nt)
        acc[mt][nt] = __builtin_amdgcn_mfma_f32_16x16x32_f16(a, wfr[nt][kt], acc[mt][nt], 0, 0, 0);
    }
#pragma unroll
  for (int mt = 0; mt < 2; ++mt)
#pragma unroll
    for (int nt = 0; nt < 4; ++nt)
#pragma unroll
      for (int e = 0; e < 4; ++e) {
        int t = t0 + tt * 32 + mt * 16 + 4 * g + e;
        out[((size_t)b * TT + t) * OUTF + nt * 16 + r] = acc[mt][nt][e] + bb[nt];
      }
}

// ---------------------------------------------------------------------------
extern "C" void kernel_launch(void* const* d_in, const int* in_sizes, int n_in,
                              void* d_out, int out_size, void* d_ws, size_t ws_size,
                              hipStream_t stream)
{
  const float* x     = (const float*)d_in[0];
  // d_in[1] = future_n (constant 512)
  const float* enc_W = (const float*)d_in[2];
  const float* enc_b = (const float*)d_in[3];
  const float* fut_W = (const float*)d_in[4];
  const float* fut_b = (const float*)d_in[5];
  const float* dec_W = (const float*)d_in[6];
  const float* dec_b = (const float*)d_in[7];
  const float* pW_ih = (const float*)d_in[8];
  const float* pW_hh = (const float*)d_in[9];
  const float* pb_ih = (const float*)d_in[10];
  const float* pb_hh = (const float*)d_in[11];
  const float* fW_ih = (const float*)d_in[12];
  const float* fW_hh = (const float*)d_in[13];
  const float* fb_ih = (const float*)d_in[14];
  const float* fb_hh = (const float*)d_in[15];
  (void)in_sizes; (void)n_in; (void)out_size;

  char* p = (char*)d_ws;
  auto alloc = [&](size_t bytes) { char* q = p; p += (bytes + 255) & ~(size_t)255; return q; };
  f16*   Wp_in = (f16*)  alloc((size_t)NG * INF * 2);
  float* bp    = (float*)alloc((size_t)NG * 4);
  f16*   Wp16  = (f16*)  alloc((size_t)NG * HD * 2);
  f16*   Wf16  = (f16*)  alloc((size_t)NG * HD * 2);
  float* bfb   = (float*)alloc((size_t)NG * 4);
  f16*   dW16  = (f16*)  alloc((size_t)OUTF * HD * 2);
  f16*   h_st  = (f16*)  alloc((size_t)B_ * HD * 2);
  float* c_st  = (float*)alloc((size_t)B_ * HD * 4);
  size_t fixed = (size_t)(p - (char*)d_ws);

  auto need = [&](int rr) {
    size_t pp = (size_t)(rr < TPAST ? rr : TPAST) * NG * B_ * 2;
    size_t hh = (size_t)rr * B_ * HD * 2;
    return pp + hh + 4096;
  };
  size_t avail = ws_size > fixed ? ws_size - fixed : 0;
  int R = 128;
  if (avail >= need(1536)) R = 1536;
  else if (avail >= need(512)) R = 512;
  else if (avail >= need(256)) R = 256;

  f16* Pbuf = (f16*)alloc((size_t)(R < TPAST ? R : TPAST) * NG * B_ * 2);
  f16* HS   = (f16*)alloc((size_t)R * B_ * HD * 2);

  eprep<<<512, 256, 0, stream>>>(enc_W, enc_b, fut_W, fut_b, dec_W,
                                 pW_ih, pW_hh, pb_ih, pb_hh,
                                 fW_ih, fW_hh, fb_ih, fb_hh,
                                 Wp_in, bp, Wp16, Wf16, bfb, dW16);

  // past phase
  for (int t0 = 0; t0 < TPAST; t0 += R) {
    int Tc = (TPAST - t0) < R ? (TPAST - t0) : R;
    epgemm<<<Tc * 8, 64, 0, stream>>>(x, Wp_in, bp, Pbuf, t0, Tc);
    erecur<<<8, 512, 0, stream>>>(Wp16, Pbuf, NG * 16, nullptr, HS, h_st, c_st, Tc, t0 == 0 ? 1 : 0);
    edec<<<(Tc / 32) * B_, 64, 0, stream>>>(HS, dW16, dec_b, (float*)d_out, t0, Tc);
  }
  // future phase (encoder folded into Wf16; bias folded into acc init)
  for (int t0 = TPAST; t0 < TT; t0 += R) {
    int Tc = (TT - t0) < R ? (TT - t0) : R;
    erecur<<<8, 512, 0, stream>>>(Wf16, nullptr, 0, bfb, HS, h_st, c_st, Tc, 0);
    edec<<<(Tc / 32) * B_, 64, 0, stream>>>(HS, dW16, dec_b, (float*)d_out, t0, Tc);
  }
}

// Round 8
// 7053.036 us; speedup vs baseline: 1.4409x; 1.4409x over previous
//
#include <hip/hip_runtime.h>

#define B_    128
#define TPAST 1024
#define FN    512
#define TT    1536
#define INF   64
#define IPF   128
#define HD    256
#define NG    1024
#define OUTF  64

typedef _Float16 f16;
typedef _Float16 f16x8 __attribute__((ext_vector_type(8)));
typedef _Float16 f16x4 __attribute__((ext_vector_type(4)));
typedef float    f32x4 __attribute__((ext_vector_type(4)));

__device__ __forceinline__ float sigm_(float x) {
  return __builtin_amdgcn_rcpf(1.f + __expf(-x));
}
__device__ __forceinline__ float tanh_(float x) {
  return 1.f - 2.f * __builtin_amdgcn_rcpf(1.f + __expf(2.f * x));
}
// Opaque 16B load (asm result can't be rematerialized -> stays resident).
__device__ __forceinline__ f16x8 oload16(const f16* p) {
  f16x8 v;
  asm volatile("global_load_dwordx4 %0, %1, off\n\ts_waitcnt vmcnt(0)"
               : "=v"(v) : "v"(p));
  return v;
}

// ---------------------------------------------------------------------------
// prep (unchanged math): fold encoder into past-input weights; fold future
// encoder into the future recurrent matrix; f16 weights.
// ---------------------------------------------------------------------------
extern "C" __global__ void eprep(
    const float* __restrict__ enc_W, const float* __restrict__ enc_b,
    const float* __restrict__ fut_W, const float* __restrict__ fut_b,
    const float* __restrict__ dec_W,
    const float* __restrict__ pW_ih, const float* __restrict__ pW_hh,
    const float* __restrict__ pb_ih, const float* __restrict__ pb_hh,
    const float* __restrict__ fW_ih, const float* __restrict__ fW_hh,
    const float* __restrict__ fb_ih, const float* __restrict__ fb_hh,
    f16* __restrict__ Wp_in, float* __restrict__ bp,
    f16* __restrict__ Wp16, f16* __restrict__ Wf16,
    float* __restrict__ bf, f16* __restrict__ dW16)
{
  int stride = gridDim.x * blockDim.x;
  int gid = blockIdx.x * blockDim.x + threadIdx.x;
  for (int i = gid; i < NG * HD; i += stride) {
    int n = i >> 8, j = i & 255;
    float s = fW_hh[i];
    for (int m = 0; m < IPF; ++m) s += fW_ih[n * IPF + m] * fut_W[m * HD + j];
    Wf16[i] = (f16)s;
    Wp16[i] = (f16)pW_hh[i];
  }
  for (int i = gid; i < NG * INF; i += stride) {
    int n = i >> 6, k = i & 63;
    float s = 0.f;
    for (int m = 0; m < IPF; ++m) s += pW_ih[n * IPF + m] * enc_W[m * INF + k];
    Wp_in[i] = (f16)s;
  }
  for (int i = gid; i < OUTF * HD; i += stride) dW16[i] = (f16)dec_W[i];
  for (int n = gid; n < NG; n += stride) {
    float s1 = pb_ih[n] + pb_hh[n], s2 = fb_ih[n] + fb_hh[n];
    for (int m = 0; m < IPF; ++m) {
      s1 += pW_ih[n * IPF + m] * enc_b[m];
      s2 += fW_ih[n * IPF + m] * fut_b[m];
    }
    bp[n] = s1; bf[n] = s2;
  }
}

// ---------------------------------------------------------------------------
// P GEMM: P = x @ Wp_in^T + bp, stored per (batch-slice, j-half) WG:
//   P[(((bt*2+jh)*Tc + tl)*512 + nl)*16 + blocal],  nl = (n>>8)*128 + (n&127)
// ---------------------------------------------------------------------------
extern "C" __global__ __launch_bounds__(64) void epgemm(
    const float* __restrict__ x, const f16* __restrict__ Wp_in,
    const float* __restrict__ bp, f16* __restrict__ P, int t0, int Tc)
{
  int wg = blockIdx.x;
  int tl = wg >> 3, bt = wg & 7;
  int t = t0 + tl;
  int l = (int)threadIdx.x, r = l & 15, g = l >> 4;
  const float* xb = x + ((size_t)(bt * 16 + r) * TPAST + t) * INF;
  f16x8 a[2];
#pragma unroll
  for (int kk = 0; kk < 2; ++kk) {
    const float* px = xb + kk * 32 + g * 8;
    f32x4 v0 = *(const f32x4*)px;
    f32x4 v1 = *(const f32x4*)(px + 4);
#pragma unroll
    for (int e = 0; e < 4; ++e) { a[kk][e] = (f16)v0[e]; a[kk][4 + e] = (f16)v1[e]; }
  }
  for (int nt = 0; nt < 64; ++nt) {
    int n = nt * 16 + r;
    f16x8 b0 = *(const f16x8*)(Wp_in + (size_t)n * INF + g * 8);
    f16x8 b1 = *(const f16x8*)(Wp_in + (size_t)n * INF + 32 + g * 8);
    f32x4 acc = {0.f, 0.f, 0.f, 0.f};
    acc = __builtin_amdgcn_mfma_f32_16x16x32_f16(a[0], b0, acc, 0, 0, 0);
    acc = __builtin_amdgcn_mfma_f32_16x16x32_f16(a[1], b1, acc, 0, 0, 0);
    float bias = bp[n];
    f16x4 hv;
#pragma unroll
    for (int e = 0; e < 4; ++e) hv[e] = (f16)(acc[e] + bias);
    int jh = (n >> 7) & 1;
    int nl = (n >> 8) * 128 + (n & 127);
    f16* Pt = P + (((size_t)(bt * 2 + jh) * Tc + tl) * 512 + nl) * 16;
    *(f16x4*)(Pt + 4 * g) = hv;
  }
}

// ---------------------------------------------------------------------------
// Persistent recurrent kernel, 2D split: 16 WGs x 256 threads (4 waves,
// 1 wave/SIMD, the empirically-verified 256-VGPR config). WG = (bs, jh):
// 16 batch rows x 128 hidden outputs; weights 256 KB/WG:
//   kt0..4 in VGPRs (40 frags = 160 regs/wave), kt5..7 in swizzled LDS (96KB).
// Per step the two half-WGs exchange 4KB of h via agent-scope atomics +
// monotonic flag (release/acquire). All 16 WGs co-resident (1 WG/CU by LDS).
// ---------------------------------------------------------------------------
extern "C" __global__ __launch_bounds__(256, 1)
void erecur(
    const f16* __restrict__ W, const f16* __restrict__ P, int pstep,
    const float* __restrict__ bias,
    f16* __restrict__ hs, f16* __restrict__ h_state, float* __restrict__ c_state,
    f16* __restrict__ Hx, unsigned int* __restrict__ flags,
    int Tc, int seq0, int init_state)
{
  __shared__ f16  Wl[512 * 96];     //  96 KB : W rows (this WG), cols 160..255
  __shared__ f16  hb[16 * HD];      //   8 KB : full h [b][j], swizzled by b
  __shared__ float cb[128 * 20];    //  10 KB : own c [j_local][b], stride 20
  __shared__ f16  bl[512];          //   1 KB : future bias (own rows)

  int tid = (int)threadIdx.x;
  int w = tid >> 6, l = tid & 63, r = l & 15, g = l >> 4;
  int wg = blockIdx.x;
  int bs = wg >> 1, jh = wg & 1;
  int b0 = bs * 16;

  // LDS-resident W cols 160..255 for this WG's 512 rows
  for (int nl = tid; nl < 512; nl += 256) {
    int n_glob = (nl >> 7) * 256 + jh * 128 + (nl & 127);
#pragma unroll
    for (int c8 = 0; c8 < 12; ++c8) {
      f16x8 v = *(const f16x8*)(W + (size_t)n_glob * HD + 160 + c8 * 8);
      *(f16x8*)&Wl[(nl * 96 + c8 * 8) ^ ((nl & 7) << 3)] = v;
    }
  }
  if (bias) {
    for (int i = tid; i < 512; i += 256) {
      int n_glob = (i >> 7) * 256 + jh * 128 + (i & 127);
      bl[i] = (f16)bias[n_glob];
    }
  }
  // Register-resident weights: kt 0..4 (160 VGPRs/wave)
  f16x8 wf[4][2][5];
#pragma unroll
  for (int ga = 0; ga < 4; ++ga)
#pragma unroll
    for (int s = 0; s < 2; ++s) {
      int n_glob = ga * 256 + jh * 128 + w * 32 + s * 16 + r;
#pragma unroll
      for (int kt = 0; kt < 5; ++kt)
        wf[ga][s][kt] = oload16(W + (size_t)n_glob * HD + kt * 32 + g * 8);
    }
  if (init_state) {
    for (int i = tid; i < 16 * HD; i += 256) hb[i ^ (((i >> 8) & 7) << 3)] = (f16)0.f;
    for (int i = tid; i < 128 * 20; i += 256) cb[i] = 0.f;
  } else {
    for (int i = tid; i < 16 * HD; i += 256) {
      int b = i >> 8, j = i & 255;
      hb[i ^ ((b & 7) << 3)] = h_state[(size_t)(b0 + b) * HD + j];
    }
    for (int i = tid; i < 16 * 128; i += 256) {
      int b = i >> 7, j = i & 127;
      cb[j * 20 + b] = c_state[(size_t)(b0 + b) * HD + jh * 128 + j];
    }
  }
  __syncthreads();

  const f16* Pw = P ? (P + (size_t)wg * Tc * pstep) : nullptr;

  for (int tl = 0; tl < Tc; ++tl) {
    int seq = seq0 + tl;
    // P loads issued at loop top: full-GEMM latency cover
    f16x4 pv[4][2];
    if (P) {
#pragma unroll
      for (int ga = 0; ga < 4; ++ga)
#pragma unroll
        for (int s = 0; s < 2; ++s) {
          int nl = ga * 128 + w * 32 + s * 16 + r;
          pv[ga][s] = *(const f16x4*)(Pw + nl * 16 + 4 * g);
        }
    }
    f32x4 acc[4][2];
#pragma unroll
    for (int ga = 0; ga < 4; ++ga)
#pragma unroll
      for (int s = 0; s < 2; ++s) acc[ga][s] = f32x4{0.f, 0.f, 0.f, 0.f};

    // kt 0..4: B from registers
#pragma unroll
    for (int kt = 0; kt < 5; ++kt) {
      f16x8 a = *(const f16x8*)&hb[(r * HD + kt * 32 + g * 8) ^ ((r & 7) << 3)];
#pragma unroll
      for (int ga = 0; ga < 4; ++ga)
#pragma unroll
        for (int s = 0; s < 2; ++s)
          acc[ga][s] = __builtin_amdgcn_mfma_f32_16x16x32_f16(a, wf[ga][s][kt], acc[ga][s], 0, 0, 0);
    }
    // kt 5..7: B from swizzled LDS
#pragma unroll
    for (int kt = 5; kt < 8; ++kt) {
      f16x8 a = *(const f16x8*)&hb[(r * HD + kt * 32 + g * 8) ^ ((r & 7) << 3)];
#pragma unroll
      for (int ga = 0; ga < 4; ++ga)
#pragma unroll
        for (int s = 0; s < 2; ++s) {
          int nl = ga * 128 + w * 32 + s * 16 + r;
          f16x8 bw = *(const f16x8*)&Wl[(nl * 96 + (kt - 5) * 32 + g * 8) ^ ((nl & 7) << 3)];
          acc[ga][s] = __builtin_amdgcn_mfma_f32_16x16x32_f16(a, bw, acc[ga][s], 0, 0, 0);
        }
    }
    __syncthreads();  // all hb reads done before any hb overwrite

    f16* HxW = Hx + ((size_t)(seq & 1) * 16 + wg) * 2048;        // own slot
#pragma unroll
    for (int s = 0; s < 2; ++s) {
      int j = w * 32 + s * 16 + r;          // j_local in [0,128)
      int jg = jh * 128 + j;                // global hidden index
      f32x4 cold = *(f32x4*)&cb[j * 20 + 4 * g];
      float gadd[4];
#pragma unroll
      for (int ga = 0; ga < 4; ++ga)
        gadd[ga] = P ? 0.f : (float)bl[ga * 128 + j];
      f32x4 cnew;
      union { unsigned long long u; f16 h4[4]; } pk;
#pragma unroll
      for (int e = 0; e < 4; ++e) {
        float xi = acc[0][s][e] + gadd[0];
        float xf = acc[1][s][e] + gadd[1];
        float xg = acc[2][s][e] + gadd[2];
        float xo = acc[3][s][e] + gadd[3];
        if (P) {
          xi += (float)pv[0][s][e]; xf += (float)pv[1][s][e];
          xg += (float)pv[2][s][e]; xo += (float)pv[3][s][e];
        }
        float ii = sigm_(xi), ff = sigm_(xf), oo = sigm_(xo), gg = tanh_(xg);
        float cn = ff * cold[e] + ii * gg;
        cnew[e] = cn;
        pk.h4[e] = (f16)(oo * tanh_(cn));
      }
      *(f32x4*)&cb[j * 20 + 4 * g] = cnew;
      // exchange write (8B agent-scope atomic, layout [j][b])
      __hip_atomic_store((unsigned long long*)(HxW + j * 16 + 4 * g), pk.u,
                         __ATOMIC_RELAXED, __HIP_MEMORY_SCOPE_AGENT);
#pragma unroll
      for (int e = 0; e < 4; ++e) {
        int b = 4 * g + e;
        hb[(b * HD + jg) ^ ((b & 7) << 3)] = pk.h4[e];
        hs[((size_t)tl * B_ + b0 + b) * HD + jg] = pk.h4[e];
      }
    }
    __syncthreads();  // drains vmcnt: all exchange stores complete

    if (tid == 0) {
      __hip_atomic_store(&flags[wg], (unsigned)(seq + 1),
                         __ATOMIC_RELEASE, __HIP_MEMORY_SCOPE_AGENT);
      while (__hip_atomic_load(&flags[wg ^ 1], __ATOMIC_ACQUIRE,
                               __HIP_MEMORY_SCOPE_AGENT) < (unsigned)(seq + 1)) {}
    }
    __syncthreads();  // partner data published

    // read partner half (512 x 8B), scatter into hb
    const f16* HxR = Hx + ((size_t)(seq & 1) * 16 + (wg ^ 1)) * 2048;
#pragma unroll
    for (int u0 = 0; u0 < 2; ++u0) {
      int u = tid + u0 * 256;
      int j = u >> 2, q = u & 3;
      union { unsigned long long u64; f16 h4[4]; } pk;
      pk.u64 = __hip_atomic_load((const unsigned long long*)(HxR + j * 16 + q * 4),
                                 __ATOMIC_RELAXED, __HIP_MEMORY_SCOPE_AGENT);
      int jg = (jh ^ 1) * 128 + j;
#pragma unroll
      for (int e = 0; e < 4; ++e) {
        int b = q * 4 + e;
        hb[(b * HD + jg) ^ ((b & 7) << 3)] = pk.h4[e];
      }
    }
    __syncthreads();  // hb fully updated for next step
    if (P) Pw += pstep;
  }
  // persist own halves of state
  for (int i = tid; i < 16 * 128; i += 256) {
    int b = i >> 7, j = i & 127;
    int jg = jh * 128 + j;
    h_state[(size_t)(b0 + b) * HD + jg] = hb[(b * HD + jg) ^ ((b & 7) << 3)];
    c_state[(size_t)(b0 + b) * HD + jg] = cb[j * 20 + b];
  }
}

// ---------------------------------------------------------------------------
// Decoder GEMM: out[b][t][o] = hs[t][b][:] @ dec_W^T + dec_b.
// ---------------------------------------------------------------------------
extern "C" __global__ __launch_bounds__(64) void edec(
    const f16* __restrict__ hs, const f16* __restrict__ dW,
    const float* __restrict__ dec_b, float* __restrict__ out, int t0, int Tc)
{
  int wg = blockIdx.x;
  int tt = wg >> 7, b = wg & 127;
  int l = (int)threadIdx.x, r = l & 15, g = l >> 4;
  f16x8 wfr[4][8];
#pragma unroll
  for (int nt = 0; nt < 4; ++nt)
#pragma unroll
    for (int kt = 0; kt < 8; ++kt)
      wfr[nt][kt] = *(const f16x8*)(dW + (size_t)(nt * 16 + r) * HD + kt * 32 + g * 8);
  float bb[4];
#pragma unroll
  for (int nt = 0; nt < 4; ++nt) bb[nt] = dec_b[nt * 16 + r];
  f32x4 acc[2][4];
  const f32x4 zero4 = {0.f, 0.f, 0.f, 0.f};
#pragma unroll
  for (int mt = 0; mt < 2; ++mt)
#pragma unroll
    for (int nt = 0; nt < 4; ++nt) acc[mt][nt] = zero4;
#pragma unroll
  for (int mt = 0; mt < 2; ++mt)
#pragma unroll
    for (int kt = 0; kt < 8; ++kt) {
      f16x8 a = *(const f16x8*)(hs + ((size_t)(tt * 32 + mt * 16 + r) * B_ + b) * HD + kt * 32 + g * 8);
#pragma unroll
      for (int nt = 0; nt < 4; ++nt)
        acc[mt][nt] = __builtin_amdgcn_mfma_f32_16x16x32_f16(a, wfr[nt][kt], acc[mt][nt], 0, 0, 0);
    }
#pragma unroll
  for (int mt = 0; mt < 2; ++mt)
#pragma unroll
    for (int nt = 0; nt < 4; ++nt)
#pragma unroll
      for (int e = 0; e < 4; ++e) {
        int t = t0 + tt * 32 + mt * 16 + 4 * g + e;
        out[((size_t)b * TT + t) * OUTF + nt * 16 + r] = acc[mt][nt][e] + bb[nt];
      }
}

// ---------------------------------------------------------------------------
extern "C" void kernel_launch(void* const* d_in, const int* in_sizes, int n_in,
                              void* d_out, int out_size, void* d_ws, size_t ws_size,
                              hipStream_t stream)
{
  const float* x     = (const float*)d_in[0];
  // d_in[1] = future_n (constant 512)
  const float* enc_W = (const float*)d_in[2];
  const float* enc_b = (const float*)d_in[3];
  const float* fut_W = (const float*)d_in[4];
  const float* fut_b = (const float*)d_in[5];
  const float* dec_W = (const float*)d_in[6];
  const float* dec_b = (const float*)d_in[7];
  const float* pW_ih = (const float*)d_in[8];
  const float* pW_hh = (const float*)d_in[9];
  const float* pb_ih = (const float*)d_in[10];
  const float* pb_hh = (const float*)d_in[11];
  const float* fW_ih = (const float*)d_in[12];
  const float* fW_hh = (const float*)d_in[13];
  const float* fb_ih = (const float*)d_in[14];
  const float* fb_hh = (const float*)d_in[15];
  (void)in_sizes; (void)n_in; (void)out_size;

  char* p = (char*)d_ws;
  auto alloc = [&](size_t bytes) { char* q = p; p += (bytes + 255) & ~(size_t)255; return q; };
  f16*   Wp_in = (f16*)  alloc((size_t)NG * INF * 2);
  float* bp    = (float*)alloc((size_t)NG * 4);
  f16*   Wp16  = (f16*)  alloc((size_t)NG * HD * 2);
  f16*   Wf16  = (f16*)  alloc((size_t)NG * HD * 2);
  float* bfb   = (float*)alloc((size_t)NG * 4);
  f16*   dW16  = (f16*)  alloc((size_t)OUTF * HD * 2);
  f16*   h_st  = (f16*)  alloc((size_t)B_ * HD * 2);
  float* c_st  = (float*)alloc((size_t)B_ * HD * 4);
  f16*   Hx    = (f16*)  alloc((size_t)2 * 16 * 2048 * 2);   // exchange, 128 KB
  unsigned int* flags = (unsigned int*)alloc(64);
  size_t fixed = (size_t)(p - (char*)d_ws);

  auto need = [&](int rr) {
    size_t pp = (size_t)(rr < TPAST ? rr : TPAST) * NG * B_ * 2;
    size_t hh = (size_t)rr * B_ * HD * 2;
    return pp + hh + 4096;
  };
  size_t avail = ws_size > fixed ? ws_size - fixed : 0;
  int R = 128;
  if (avail >= need(1536)) R = 1536;
  else if (avail >= need(512)) R = 512;
  else if (avail >= need(256)) R = 256;

  f16* Pbuf = (f16*)alloc((size_t)(R < TPAST ? R : TPAST) * NG * B_ * 2);
  f16* HS   = (f16*)alloc((size_t)R * B_ * HD * 2);

  hipMemsetAsync(flags, 0, 64, stream);   // reset exchange flags each launch

  eprep<<<512, 256, 0, stream>>>(enc_W, enc_b, fut_W, fut_b, dec_W,
                                 pW_ih, pW_hh, pb_ih, pb_hh,
                                 fW_ih, fW_hh, fb_ih, fb_hh,
                                 Wp_in, bp, Wp16, Wf16, bfb, dW16);

  // past phase
  for (int t0 = 0; t0 < TPAST; t0 += R) {
    int Tc = (TPAST - t0) < R ? (TPAST - t0) : R;
    epgemm<<<Tc * 8, 64, 0, stream>>>(x, Wp_in, bp, Pbuf, t0, Tc);
    erecur<<<16, 256, 0, stream>>>(Wp16, Pbuf, 512 * 16, nullptr, HS, h_st, c_st,
                                   Hx, flags, Tc, t0, t0 == 0 ? 1 : 0);
    edec<<<(Tc / 32) * B_, 64, 0, stream>>>(HS, dW16, dec_b, (float*)d_out, t0, Tc);
  }
  // future phase (encoder folded into Wf16; bias staged to LDS in-kernel)
  for (int t0 = TPAST; t0 < TT; t0 += R) {
    int Tc = (TT - t0) < R ? (TT - t0) : R;
    erecur<<<16, 256, 0, stream>>>(Wf16, nullptr, 0, bfb, HS, h_st, c_st,
                                   Hx, flags, Tc, t0, 0);
    edec<<<(Tc / 32) * B_, 64, 0, stream>>>(HS, dW16, dec_b, (float*)d_out, t0, Tc);
  }
}

// Round 9
// 6443.244 us; speedup vs baseline: 1.5773x; 1.0946x over previous
//
#include <hip/hip_runtime.h>

#define B_    128
#define TPAST 1024
#define FN    512
#define TT    1536
#define INF   64
#define IPF   128
#define HD    256
#define NG    1024
#define OUTF  64

typedef _Float16 f16;
typedef _Float16 f16x8 __attribute__((ext_vector_type(8)));
typedef _Float16 f16x4 __attribute__((ext_vector_type(4)));
typedef float    f32x4 __attribute__((ext_vector_type(4)));

template<int N> struct ic { static constexpr int value = N; };

__device__ __forceinline__ float sigm_(float x) {
  return __builtin_amdgcn_rcpf(1.f + __expf(-x));
}
__device__ __forceinline__ float tanh_(float x) {
  return 1.f - 2.f * __builtin_amdgcn_rcpf(1.f + __expf(2.f * x));
}
// Opaque 16B load (asm result can't be rematerialized -> stays resident).
__device__ __forceinline__ f16x8 oload16(const f16* p) {
  f16x8 v;
  asm volatile("global_load_dwordx4 %0, %1, off\n\ts_waitcnt vmcnt(0)"
               : "=v"(v) : "v"(p));
  return v;
}

// ---------------------------------------------------------------------------
// prep (unchanged): fold encoder into past-input weights; fold future encoder
// into the future recurrent matrix; f16 weights.
// ---------------------------------------------------------------------------
extern "C" __global__ void eprep(
    const float* __restrict__ enc_W, const float* __restrict__ enc_b,
    const float* __restrict__ fut_W, const float* __restrict__ fut_b,
    const float* __restrict__ dec_W,
    const float* __restrict__ pW_ih, const float* __restrict__ pW_hh,
    const float* __restrict__ pb_ih, const float* __restrict__ pb_hh,
    const float* __restrict__ fW_ih, const float* __restrict__ fW_hh,
    const float* __restrict__ fb_ih, const float* __restrict__ fb_hh,
    f16* __restrict__ Wp_in, float* __restrict__ bp,
    f16* __restrict__ Wp16, f16* __restrict__ Wf16,
    float* __restrict__ bf, f16* __restrict__ dW16)
{
  int stride = gridDim.x * blockDim.x;
  int gid = blockIdx.x * blockDim.x + threadIdx.x;
  for (int i = gid; i < NG * HD; i += stride) {
    int n = i >> 8, j = i & 255;
    float s = fW_hh[i];
    for (int m = 0; m < IPF; ++m) s += fW_ih[n * IPF + m] * fut_W[m * HD + j];
    Wf16[i] = (f16)s;
    Wp16[i] = (f16)pW_hh[i];
  }
  for (int i = gid; i < NG * INF; i += stride) {
    int n = i >> 6, k = i & 63;
    float s = 0.f;
    for (int m = 0; m < IPF; ++m) s += pW_ih[n * IPF + m] * enc_W[m * INF + k];
    Wp_in[i] = (f16)s;
  }
  for (int i = gid; i < OUTF * HD; i += stride) dW16[i] = (f16)dec_W[i];
  for (int n = gid; n < NG; n += stride) {
    float s1 = pb_ih[n] + pb_hh[n], s2 = fb_ih[n] + fb_hh[n];
    for (int m = 0; m < IPF; ++m) {
      s1 += pW_ih[n * IPF + m] * enc_b[m];
      s2 += fW_ih[n * IPF + m] * fut_b[m];
    }
    bp[n] = s1; bf[n] = s2;
  }
}

// ---------------------------------------------------------------------------
// P GEMM: P = x @ Wp_in^T + bp, stored per (jh, batch-slice) WG slot
//   slot = jh*8 + bt  (matches erecur's same-XCD pair mapping wg = jh*8+bs)
//   P[((slot*Tc + tl)*512 + nl)*16 + blocal],  nl = (n>>8)*128 + (n&127)
// ---------------------------------------------------------------------------
extern "C" __global__ __launch_bounds__(64) void epgemm(
    const float* __restrict__ x, const f16* __restrict__ Wp_in,
    const float* __restrict__ bp, f16* __restrict__ P, int t0, int Tc)
{
  int wg = blockIdx.x;
  int tl = wg >> 3, bt = wg & 7;
  int t = t0 + tl;
  int l = (int)threadIdx.x, r = l & 15, g = l >> 4;
  const float* xb = x + ((size_t)(bt * 16 + r) * TPAST + t) * INF;
  f16x8 a[2];
#pragma unroll
  for (int kk = 0; kk < 2; ++kk) {
    const float* px = xb + kk * 32 + g * 8;
    f32x4 v0 = *(const f32x4*)px;
    f32x4 v1 = *(const f32x4*)(px + 4);
#pragma unroll
    for (int e = 0; e < 4; ++e) { a[kk][e] = (f16)v0[e]; a[kk][4 + e] = (f16)v1[e]; }
  }
  for (int nt = 0; nt < 64; ++nt) {
    int n = nt * 16 + r;
    f16x8 b0 = *(const f16x8*)(Wp_in + (size_t)n * INF + g * 8);
    f16x8 b1 = *(const f16x8*)(Wp_in + (size_t)n * INF + 32 + g * 8);
    f32x4 acc = {0.f, 0.f, 0.f, 0.f};
    acc = __builtin_amdgcn_mfma_f32_16x16x32_f16(a[0], b0, acc, 0, 0, 0);
    acc = __builtin_amdgcn_mfma_f32_16x16x32_f16(a[1], b1, acc, 0, 0, 0);
    float bias = bp[n];
    f16x4 hv;
#pragma unroll
    for (int e = 0; e < 4; ++e) hv[e] = (f16)(acc[e] + bias);
    int jh = (n >> 7) & 1;
    int nl = (n >> 8) * 128 + (n & 127);
    f16* Pt = P + (((size_t)(jh * 8 + bt) * Tc + tl) * 512 + nl) * 16;
    *(f16x4*)(Pt + 4 * g) = hv;
  }
}

// ---------------------------------------------------------------------------
// Persistent recurrent kernel, 2D split with same-XCD pairing and pipelined
// exchange. 16 WGs x 256 threads (4 waves, 1 wave/SIMD). wg = jh*8 + bs,
// partner = wg^8 (same XCD under round-robin dispatch). Weights 256 KB/WG:
// kt0..4 in VGPRs (160/wave), kt5..7 in swizzled LDS. h double-buffered by
// step parity in LDS. Per step: own-half k-tiles -> spin+scatter -> partner
// k-tiles; 2 barriers/step; hs stores deferred past the flag release.
// ---------------------------------------------------------------------------
extern "C" __global__ __launch_bounds__(256, 1)
void erecur(
    const f16* __restrict__ W, const f16* __restrict__ P, int pstep,
    const float* __restrict__ bias,
    f16* __restrict__ hs, f16* __restrict__ h_state, float* __restrict__ c_state,
    f16* __restrict__ Hx, unsigned int* __restrict__ flags,
    int Tc, int seq0, int init_state)
{
  __shared__ f16  Wl[512 * 96];     //  96 KB : W rows (this WG), cols 160..255
  __shared__ f16  hb[2][16 * HD];   //  16 KB : h [b][j] double-buffered, swizzled
  __shared__ float cb[128 * 20];    //  10 KB : own c [j_local][b], stride 20
  __shared__ f16  bl[512];          //   1 KB : future bias (own rows)

  int tid = (int)threadIdx.x;
  int w = tid >> 6, l = tid & 63, r = l & 15, g = l >> 4;
  int wg = blockIdx.x;
  int bs = wg & 7, jh = wg >> 3;
  int b0 = bs * 16;
  int pwg = wg ^ 8;

  // LDS-resident W cols 160..255 for this WG's 512 rows
  for (int nl = tid; nl < 512; nl += 256) {
    int n_glob = (nl >> 7) * 256 + jh * 128 + (nl & 127);
#pragma unroll
    for (int c8 = 0; c8 < 12; ++c8) {
      f16x8 v = *(const f16x8*)(W + (size_t)n_glob * HD + 160 + c8 * 8);
      *(f16x8*)&Wl[(nl * 96 + c8 * 8) ^ ((nl & 7) << 3)] = v;
    }
  }
  if (bias) {
    for (int i = tid; i < 512; i += 256) {
      int n_glob = (i >> 7) * 256 + jh * 128 + (i & 127);
      bl[i] = (f16)bias[n_glob];
    }
  }
  // Register-resident weights: kt 0..4 (160 VGPRs/wave)
  f16x8 wf[4][2][5];
#pragma unroll
  for (int ga = 0; ga < 4; ++ga)
#pragma unroll
    for (int s = 0; s < 2; ++s) {
      int n_glob = ga * 256 + jh * 128 + w * 32 + s * 16 + r;
#pragma unroll
      for (int kt = 0; kt < 5; ++kt)
        wf[ga][s][kt] = oload16(W + (size_t)n_glob * HD + kt * 32 + g * 8);
    }
  // Prologue: full h(seq0) into hb[seq0&1]; own c into cb
  int cur0 = seq0 & 1;
  if (init_state) {
    for (int i = tid; i < 16 * HD; i += 256) hb[cur0][i ^ (((i >> 8) & 7) << 3)] = (f16)0.f;
    for (int i = tid; i < 128 * 20; i += 256) cb[i] = 0.f;
  } else {
    for (int i = tid; i < 16 * HD; i += 256) {
      int b = i >> 8, j = i & 255;
      hb[cur0][i ^ ((b & 7) << 3)] = h_state[(size_t)(b0 + b) * HD + j];
    }
    for (int i = tid; i < 16 * 128; i += 256) {
      int b = i >> 7, j = i & 127;
      cb[j * 20 + b] = c_state[(size_t)(b0 + b) * HD + jh * 128 + j];
    }
  }
  __syncthreads();

  const f16* Pw = P ? (P + (size_t)wg * Tc * pstep) : nullptr;

  for (int tl = 0; tl < Tc; ++tl) {
    int v = seq0 + tl;                      // h version consumed this step
    const f16* hbc = hb[v & 1];

    // P loads at loop top (latency hidden under the whole GEMM)
    f16x4 pv[4][2];
    if (P) {
#pragma unroll
      for (int ga = 0; ga < 4; ++ga)
#pragma unroll
        for (int s = 0; s < 2; ++s) {
          int nl = ga * 128 + w * 32 + s * 16 + r;
          pv[ga][s] = *(const f16x4*)(Pw + nl * 16 + 4 * g);
        }
    }
    f32x4 acc[4][2];
#pragma unroll
    for (int ga = 0; ga < 4; ++ga)
#pragma unroll
      for (int s = 0; s < 2; ++s) acc[ga][s] = f32x4{0.f, 0.f, 0.f, 0.f};

    auto gemm_kt = [&](auto ktc) {
      constexpr int KT = decltype(ktc)::value;
      f16x8 a = *(const f16x8*)&hbc[(r * HD + KT * 32 + g * 8) ^ ((r & 7) << 3)];
#pragma unroll
      for (int ga = 0; ga < 4; ++ga)
#pragma unroll
        for (int s = 0; s < 2; ++s) {
          if constexpr (KT < 5) {
            acc[ga][s] = __builtin_amdgcn_mfma_f32_16x16x32_f16(a, wf[ga][s][KT], acc[ga][s], 0, 0, 0);
          } else {
            int nl = ga * 128 + w * 32 + s * 16 + r;
            f16x8 bw = *(const f16x8*)&Wl[(nl * 96 + (KT - 5) * 32 + g * 8) ^ ((nl & 7) << 3)];
            acc[ga][s] = __builtin_amdgcn_mfma_f32_16x16x32_f16(a, bw, acc[ga][s], 0, 0, 0);
          }
        }
    };

    // Own-half k-tiles (data produced locally last step)
    if (jh == 0) { gemm_kt(ic<0>{}); gemm_kt(ic<1>{}); gemm_kt(ic<2>{}); gemm_kt(ic<3>{}); }
    else         { gemm_kt(ic<4>{}); gemm_kt(ic<5>{}); gemm_kt(ic<6>{}); gemm_kt(ic<7>{}); }

    // Receive partner half of h(v) (skip tl==0: prologue loaded full h)
    if (tl > 0) {
      unsigned tgt = (unsigned)v;
      while (__hip_atomic_load(&flags[pwg], __ATOMIC_ACQUIRE,
                               __HIP_MEMORY_SCOPE_AGENT) < tgt)
        __builtin_amdgcn_s_sleep(1);
      const f16* HxR = Hx + ((size_t)(v & 1) * 16 + pwg) * 2048;
      f16* hbw = hb[v & 1];
#pragma unroll
      for (int u0 = 0; u0 < 2; ++u0) {
        int u = tid + u0 * 256;
        int j = u >> 2, q = u & 3;
        union { unsigned long long u64; f16 h4[4]; } pk;
        pk.u64 = __hip_atomic_load((const unsigned long long*)(HxR + j * 16 + q * 4),
                                   __ATOMIC_RELAXED, __HIP_MEMORY_SCOPE_AGENT);
        int jg = (jh ^ 1) * 128 + j;
#pragma unroll
        for (int e = 0; e < 4; ++e) {
          int b = q * 4 + e;
          hbw[(b * HD + jg) ^ ((b & 7) << 3)] = pk.h4[e];
        }
      }
      __syncthreads();   // B1: scatter visible to all waves
    }

    // Partner-half k-tiles
    if (jh == 0) { gemm_kt(ic<4>{}); gemm_kt(ic<5>{}); gemm_kt(ic<6>{}); gemm_kt(ic<7>{}); }
    else         { gemm_kt(ic<0>{}); gemm_kt(ic<1>{}); gemm_kt(ic<2>{}); gemm_kt(ic<3>{}); }

    // Elementwise -> h(v+1) own half. Writes go to hb[(v+1)&1] (other buffer)
    // so no barrier is needed between GEMM reads and these writes.
    f16* hbn = hb[(v + 1) & 1];
    f16* HxW = Hx + ((size_t)((v + 1) & 1) * 16 + wg) * 2048;
    f16 hsave[2][4];
#pragma unroll
    for (int s = 0; s < 2; ++s) {
      int j = w * 32 + s * 16 + r;          // j_local in [0,128)
      int jg = jh * 128 + j;
      f32x4 cold = *(f32x4*)&cb[j * 20 + 4 * g];
      float gadd[4];
#pragma unroll
      for (int ga = 0; ga < 4; ++ga)
        gadd[ga] = P ? 0.f : (float)bl[ga * 128 + j];
      f32x4 cnew;
      union { unsigned long long u; f16 h4[4]; } pk;
#pragma unroll
      for (int e = 0; e < 4; ++e) {
        float xi = acc[0][s][e] + gadd[0];
        float xf = acc[1][s][e] + gadd[1];
        float xg = acc[2][s][e] + gadd[2];
        float xo = acc[3][s][e] + gadd[3];
        if (P) {
          xi += (float)pv[0][s][e]; xf += (float)pv[1][s][e];
          xg += (float)pv[2][s][e]; xo += (float)pv[3][s][e];
        }
        float ii = sigm_(xi), ff = sigm_(xf), oo = sigm_(xo), gg = tanh_(xg);
        float cn = ff * cold[e] + ii * gg;
        cnew[e] = cn;
        pk.h4[e] = (f16)(oo * tanh_(cn));
        hsave[s][e] = pk.h4[e];
      }
      *(f32x4*)&cb[j * 20 + 4 * g] = cnew;
      __hip_atomic_store((unsigned long long*)(HxW + j * 16 + 4 * g), pk.u,
                         __ATOMIC_RELAXED, __HIP_MEMORY_SCOPE_AGENT);
#pragma unroll
      for (int e = 0; e < 4; ++e) {
        int b = 4 * g + e;
        hbn[(b * HD + jg) ^ ((b & 7) << 3)] = pk.h4[e];
      }
    }
    __syncthreads();   // B2: Hx stores drained (vmcnt) + hbn writes visible

    if (tid == 0)
      __hip_atomic_store(&flags[wg], (unsigned)(v + 1),
                         __ATOMIC_RELEASE, __HIP_MEMORY_SCOPE_AGENT);

    // hs stores deferred past the flag release (off the partner's critical path)
#pragma unroll
    for (int s = 0; s < 2; ++s) {
      int jg = jh * 128 + w * 32 + s * 16 + r;
#pragma unroll
      for (int e = 0; e < 4; ++e)
        hs[((size_t)tl * B_ + b0 + 4 * g + e) * HD + jg] = hsave[s][e];
    }
    if (P) Pw += pstep;
  }
  // persist own halves of state (h from the last-written buffer)
  const f16* hbf = hb[(seq0 + Tc) & 1];
  for (int i = tid; i < 16 * 128; i += 256) {
    int b = i >> 7, j = i & 127;
    int jg = jh * 128 + j;
    h_state[(size_t)(b0 + b) * HD + jg] = hbf[(b * HD + jg) ^ ((b & 7) << 3)];
    c_state[(size_t)(b0 + b) * HD + jg] = cb[j * 20 + b];
  }
}

// ---------------------------------------------------------------------------
// Decoder GEMM: out[b][t][o] = hs[t][b][:] @ dec_W^T + dec_b.
// ---------------------------------------------------------------------------
extern "C" __global__ __launch_bounds__(64) void edec(
    const f16* __restrict__ hs, const f16* __restrict__ dW,
    const float* __restrict__ dec_b, float* __restrict__ out, int t0, int Tc)
{
  int wg = blockIdx.x;
  int tt = wg >> 7, b = wg & 127;
  int l = (int)threadIdx.x, r = l & 15, g = l >> 4;
  f16x8 wfr[4][8];
#pragma unroll
  for (int nt = 0; nt < 4; ++nt)
#pragma unroll
    for (int kt = 0; kt < 8; ++kt)
      wfr[nt][kt] = *(const f16x8*)(dW + (size_t)(nt * 16 + r) * HD + kt * 32 + g * 8);
  float bb[4];
#pragma unroll
  for (int nt = 0; nt < 4; ++nt) bb[nt] = dec_b[nt * 16 + r];
  f32x4 acc[2][4];
  const f32x4 zero4 = {0.f, 0.f, 0.f, 0.f};
#pragma unroll
  for (int mt = 0; mt < 2; ++mt)
#pragma unroll
    for (int nt = 0; nt < 4; ++nt) acc[mt][nt] = zero4;
#pragma unroll
  for (int mt = 0; mt < 2; ++mt)
#pragma unroll
    for (int kt = 0; kt < 8; ++kt) {
      f16x8 a = *(const f16x8*)(hs + ((size_t)(tt * 32 + mt * 16 + r) * B_ + b) * HD + kt * 32 + g * 8);
#pragma unroll
      for (int nt = 0; nt < 4; ++nt)
        acc[mt][nt] = __builtin_amdgcn_mfma_f32_16x16x32_f16(a, wfr[nt][kt], acc[mt][nt], 0, 0, 0);
    }
#pragma unroll
  for (int mt = 0; mt < 2; ++mt)
#pragma unroll
    for (int nt = 0; nt < 4; ++nt)
#pragma unroll
      for (int e = 0; e < 4; ++e) {
        int t = t0 + tt * 32 + mt * 16 + 4 * g + e;
        out[((size_t)b * TT + t) * OUTF + nt * 16 + r] = acc[mt][nt][e] + bb[nt];
      }
}

// ---------------------------------------------------------------------------
extern "C" void kernel_launch(void* const* d_in, const int* in_sizes, int n_in,
                              void* d_out, int out_size, void* d_ws, size_t ws_size,
                              hipStream_t stream)
{
  const float* x     = (const float*)d_in[0];
  // d_in[1] = future_n (constant 512)
  const float* enc_W = (const float*)d_in[2];
  const float* enc_b = (const float*)d_in[3];
  const float* fut_W = (const float*)d_in[4];
  const float* fut_b = (const float*)d_in[5];
  const float* dec_W = (const float*)d_in[6];
  const float* dec_b = (const float*)d_in[7];
  const float* pW_ih = (const float*)d_in[8];
  const float* pW_hh = (const float*)d_in[9];
  const float* pb_ih = (const float*)d_in[10];
  const float* pb_hh = (const float*)d_in[11];
  const float* fW_ih = (const float*)d_in[12];
  const float* fW_hh = (const float*)d_in[13];
  const float* fb_ih = (const float*)d_in[14];
  const float* fb_hh = (const float*)d_in[15];
  (void)in_sizes; (void)n_in; (void)out_size;

  char* p = (char*)d_ws;
  auto alloc = [&](size_t bytes) { char* q = p; p += (bytes + 255) & ~(size_t)255; return q; };
  f16*   Wp_in = (f16*)  alloc((size_t)NG * INF * 2);
  float* bp    = (float*)alloc((size_t)NG * 4);
  f16*   Wp16  = (f16*)  alloc((size_t)NG * HD * 2);
  f16*   Wf16  = (f16*)  alloc((size_t)NG * HD * 2);
  float* bfb   = (float*)alloc((size_t)NG * 4);
  f16*   dW16  = (f16*)  alloc((size_t)OUTF * HD * 2);
  f16*   h_st  = (f16*)  alloc((size_t)B_ * HD * 2);
  float* c_st  = (float*)alloc((size_t)B_ * HD * 4);
  f16*   Hx    = (f16*)  alloc((size_t)2 * 16 * 2048 * 2);   // exchange, 128 KB
  unsigned int* flags = (unsigned int*)alloc(64);
  size_t fixed = (size_t)(p - (char*)d_ws);

  auto need = [&](int rr) {
    size_t pp = (size_t)(rr < TPAST ? rr : TPAST) * NG * B_ * 2;
    size_t hh = (size_t)rr * B_ * HD * 2;
    return pp + hh + 4096;
  };
  size_t avail = ws_size > fixed ? ws_size - fixed : 0;
  int R = 128;
  if (avail >= need(1536)) R = 1536;
  else if (avail >= need(512)) R = 512;
  else if (avail >= need(256)) R = 256;

  f16* Pbuf = (f16*)alloc((size_t)(R < TPAST ? R : TPAST) * NG * B_ * 2);
  f16* HS   = (f16*)alloc((size_t)R * B_ * HD * 2);

  hipMemsetAsync(flags, 0, 64, stream);   // reset exchange flags each launch

  eprep<<<512, 256, 0, stream>>>(enc_W, enc_b, fut_W, fut_b, dec_W,
                                 pW_ih, pW_hh, pb_ih, pb_hh,
                                 fW_ih, fW_hh, fb_ih, fb_hh,
                                 Wp_in, bp, Wp16, Wf16, bfb, dW16);

  // past phase
  for (int t0 = 0; t0 < TPAST; t0 += R) {
    int Tc = (TPAST - t0) < R ? (TPAST - t0) : R;
    epgemm<<<Tc * 8, 64, 0, stream>>>(x, Wp_in, bp, Pbuf, t0, Tc);
    erecur<<<16, 256, 0, stream>>>(Wp16, Pbuf, 512 * 16, nullptr, HS, h_st, c_st,
                                   Hx, flags, Tc, t0, t0 == 0 ? 1 : 0);
    edec<<<(Tc / 32) * B_, 64, 0, stream>>>(HS, dW16, dec_b, (float*)d_out, t0, Tc);
  }
  // future phase (encoder folded into Wf16; bias staged to LDS in-kernel)
  for (int t0 = TPAST; t0 < TT; t0 += R) {
    int Tc = (TT - t0) < R ? (TT - t0) : R;
    erecur<<<16, 256, 0, stream>>>(Wf16, nullptr, 0, bfb, HS, h_st, c_st,
                                   Hx, flags, Tc, t0, 0);
    edec<<<(Tc / 32) * B_, 64, 0, stream>>>(HS, dW16, dec_b, (float*)d_out, t0, Tc);
  }
}